// Round 1
// baseline (1633.266 us; speedup 1.0000x reference)
//
#include <hip/hip_runtime.h>
#include <math.h>

#define N_TOK 2048
#define DIM   1024
#define NH    16
#define HD_   64
#define SEQ   1024
#define NEXP  31
#define INTER_ 1024

__device__ __forceinline__ float gelu_f(float x){
  return 0.5f*x*(1.0f + erff(x*0.70710678118654752f));
}

// ===================== RMSNorm =====================
__global__ __launch_bounds__(256) void rmsnorm_k(const float* __restrict__ x,
    const float* __restrict__ gamma, float* __restrict__ out)
{
  const int t = blockIdx.x, tid = threadIdx.x;
  const float* xr = x + (size_t)t * DIM;
  float4 xv = *(const float4*)(xr + tid*4);
  float ss = xv.x*xv.x + xv.y*xv.y + xv.z*xv.z + xv.w*xv.w;
  #pragma unroll
  for (int off = 32; off; off >>= 1) ss += __shfl_down(ss, off);
  __shared__ float red[4];
  if ((tid & 63) == 0) red[tid >> 6] = ss;
  __syncthreads();
  float inv = rsqrtf((red[0]+red[1]+red[2]+red[3]) * (1.0f/DIM) + 1e-5f);
  float4 gv = *(const float4*)(gamma + tid*4);
  float4 o;
  o.x = xv.x*inv*gv.x; o.y = xv.y*inv*gv.y; o.z = xv.z*inv*gv.z; o.w = xv.w*inv*gv.w;
  *(float4*)(out + (size_t)t*DIM + tid*4) = o;
}

// ===================== fp32 tiled GEMM =====================
// C[N,M] = fuse(A[N,K] @ W[K,M] + bias)
// FUSE 0: none; 1: gelu; 2: +add1; 3: +add1+add2
template<int FUSE>
__global__ __launch_bounds__(256) void gemm_k(
    const float* __restrict__ A, const float* __restrict__ W,
    const float* __restrict__ bias, float* __restrict__ C,
    const float* __restrict__ add1, const float* __restrict__ add2,
    int K, int M)
{
  __shared__ float As[16][64];
  __shared__ float Ws[16][64];
  const int tid = threadIdx.x;
  const int tm = tid >> 4, tn = tid & 15;
  const int row0 = blockIdx.y * 64, col0 = blockIdx.x * 64;
  const int lm = tid >> 2, lk = (tid & 3) * 4;   // A tile: row lm, k lk..lk+3
  const int wk = tid >> 4, wn = (tid & 15) * 4;  // W tile: k wk, n wn..wn+3
  float acc[4][4] = {};
  for (int k0 = 0; k0 < K; k0 += 16) {
    float4 av = *(const float4*)(A + (size_t)(row0+lm)*K + k0 + lk);
    float4 wv = *(const float4*)(W + (size_t)(k0+wk)*M + col0 + wn);
    As[lk+0][lm] = av.x; As[lk+1][lm] = av.y; As[lk+2][lm] = av.z; As[lk+3][lm] = av.w;
    *(float4*)&Ws[wk][wn] = wv;
    __syncthreads();
    #pragma unroll
    for (int kk = 0; kk < 16; kk++) {
      float a[4], b[4];
      *(float4*)a = *(const float4*)&As[kk][tm*4];
      *(float4*)b = *(const float4*)&Ws[kk][tn*4];
      #pragma unroll
      for (int i = 0; i < 4; i++)
        #pragma unroll
        for (int j = 0; j < 4; j++) acc[i][j] += a[i]*b[j];
    }
    __syncthreads();
  }
  #pragma unroll
  for (int i = 0; i < 4; i++) {
    int r = row0 + tm*4 + i;
    #pragma unroll
    for (int j = 0; j < 4; j++) {
      int c = col0 + tn*4 + j;
      float v = acc[i][j] + bias[c];
      if (FUSE == 1) v = gelu_f(v);
      if (FUSE == 2) v += add1[(size_t)r*M + c];
      if (FUSE == 3) v += add1[(size_t)r*M + c] + add2[(size_t)r*M + c];
      C[(size_t)r*M + c] = v;
    }
  }
}

// ===================== RoPE (in-place on q,k) =====================
__global__ __launch_bounds__(256) void rope_k(float* __restrict__ q, float* __restrict__ k,
    const float* __restrict__ theta)
{
  const int tid = threadIdx.x;
  const int p = blockIdx.x * 8 + (tid >> 5);  // (token,head) pair
  const int j = tid & 31;
  const int t = p >> 4, h = p & 15;
  const int s = t & (SEQ - 1);
  float ang = (float)s * theta[j];
  float sn, c;
  sincosf(ang, &sn, &c);
  size_t base = (size_t)t*DIM + h*HD_;
  float q1 = q[base + 2*j], q2 = q[base + 2*j + 1];
  float k1 = k[base + 2*j], k2 = k[base + 2*j + 1];
  __syncthreads();
  q[base + j]      = q1*c - q2*sn;
  q[base + j + 32] = q1*sn + q2*c;
  k[base + j]      = k1*c - k2*sn;
  k[base + j + 32] = k1*sn + k2*c;
}

// ===================== Flash attention (causal) =====================
__global__ __launch_bounds__(256) void attn_k(const float* __restrict__ Q,
    const float* __restrict__ Kg, const float* __restrict__ V, float* __restrict__ ctx)
{
  const int qt = blockIdx.x;        // 16 q-tiles
  const int bh = blockIdx.y;        // 32 (b,h)
  const int b = bh >> 4, h = bh & 15;
  const int tid = threadIdx.x;
  const int r = tid >> 2, seg = tid & 3;
  __shared__ float Qs[64][64];
  __shared__ float Ks[64][64];
  __shared__ float Vs[64][64];
  __shared__ float Ps[64][65];
  const size_t headoff = (size_t)h * HD_;
  for (int e = tid; e < 64*64; e += 256) {
    int rr = e >> 6, dd = e & 63;
    Qs[rr][dd] = Q[(size_t)(b*SEQ + qt*64 + rr)*DIM + headoff + dd];
  }
  float O[16];
  #pragma unroll
  for (int j = 0; j < 16; j++) O[j] = 0.f;
  float mi = -INFINITY, li = 0.f;
  const float scale = 0.125f;
  for (int kt = 0; kt <= qt; kt++) {
    __syncthreads();
    for (int e = tid; e < 64*64; e += 256) {
      int rr = e >> 6, dd = e & 63;
      Ks[rr][dd] = Kg[(size_t)(b*SEQ + kt*64 + rr)*DIM + headoff + dd];
      Vs[rr][dd] = V [(size_t)(b*SEQ + kt*64 + rr)*DIM + headoff + dd];
    }
    __syncthreads();
    float sc[16];
    #pragma unroll
    for (int c = 0; c < 16; c++) sc[c] = 0.f;
    for (int dd = 0; dd < 64; dd += 4) {
      float qv[4]; *(float4*)qv = *(const float4*)&Qs[r][dd];
      #pragma unroll
      for (int c = 0; c < 16; c++) {
        float kv[4]; *(float4*)kv = *(const float4*)&Ks[seg*16 + c][dd];
        sc[c] += qv[0]*kv[0] + qv[1]*kv[1] + qv[2]*kv[2] + qv[3]*kv[3];
      }
    }
    float tmax = -INFINITY;
    #pragma unroll
    for (int c = 0; c < 16; c++) {
      int col = seg*16 + c;
      if (kt == qt && col > r) sc[c] = -INFINITY;
      else { sc[c] *= scale; tmax = fmaxf(tmax, sc[c]); }
    }
    tmax = fmaxf(tmax, __shfl_xor(tmax, 1));
    tmax = fmaxf(tmax, __shfl_xor(tmax, 2));
    float mnew = fmaxf(mi, tmax);
    float alpha = expf(mi - mnew);
    float lsum = 0.f;
    #pragma unroll
    for (int c = 0; c < 16; c++) {
      float p = expf(sc[c] - mnew);
      Ps[r][seg*16 + c] = p;
      lsum += p;
    }
    lsum += __shfl_xor(lsum, 1);
    lsum += __shfl_xor(lsum, 2);
    li = li * alpha + lsum;
    mi = mnew;
    #pragma unroll
    for (int j = 0; j < 16; j++) O[j] *= alpha;
    __syncthreads();
    for (int cc = 0; cc < 64; cc++) {
      float p = Ps[r][cc];
      const float* vrow = &Vs[cc][seg*16];
      #pragma unroll
      for (int j = 0; j < 16; j += 4) {
        float vv[4]; *(float4*)vv = *(const float4*)&vrow[j];
        O[j]   += p*vv[0]; O[j+1] += p*vv[1]; O[j+2] += p*vv[2]; O[j+3] += p*vv[3];
      }
    }
  }
  float invl = 1.0f / li;
  size_t obase = (size_t)(b*SEQ + qt*64 + r)*DIM + headoff + seg*16;
  #pragma unroll
  for (int j = 0; j < 16; j++) ctx[obase + j] = O[j]*invl;
}

// ===================== Router + top-3 bucketing =====================
__global__ __launch_bounds__(64) void router_k(const float* __restrict__ an,
    const float* __restrict__ rw, const float* __restrict__ rb,
    int* __restrict__ counts, int* __restrict__ tok_list, float* __restrict__ gate_list)
{
  const int t = blockIdx.x, tid = threadIdx.x;
  __shared__ float lg[NEXP];
  if (tid < NEXP) {
    float acc = 0.f;
    const float* ar = an + (size_t)t*DIM;
    for (int d = 0; d < DIM; d++) acc += ar[d] * rw[d*NEXP + tid];
    lg[tid] = acc + rb[tid];
  }
  __syncthreads();
  if (tid == 0) {
    float m = -1e30f;
    for (int e = 0; e < NEXP; e++) m = fmaxf(m, lg[e]);
    float den = 0.f;
    for (int e = 0; e < NEXP; e++) den += expf(lg[e] - m);
    float inv = 1.0f/den;
    bool used[NEXP] = {};
    for (int kk = 0; kk < 3; kk++) {
      int best = 0; float bv = -1e30f;
      for (int e = 0; e < NEXP; e++) if (!used[e] && lg[e] > bv) { bv = lg[e]; best = e; }
      used[best] = true;
      float gate = expf(lg[best] - m)*inv;
      int slot = atomicAdd(&counts[best], 1);
      tok_list[best*N_TOK + slot] = t;
      gate_list[best*N_TOK + slot] = gate;
    }
  }
}

__global__ void scan_k(const int* __restrict__ counts, int* __restrict__ offs){
  if (threadIdx.x == 0) { int s = 0; for (int e = 0; e < NEXP; e++){ offs[e] = s; s += counts[e]; } }
}

// ===================== MoE expert FFN (gathered GEMMs) =====================
__global__ __launch_bounds__(256) void moe_ffn1_k(const float* __restrict__ an,
    const float* __restrict__ re_w1, const float* __restrict__ re_b1,
    const int* __restrict__ counts, const int* __restrict__ offs,
    const int* __restrict__ tok_list, float* __restrict__ h)
{
  const int e = blockIdx.z;
  const int cnt = counts[e];
  const int row0 = blockIdx.y * 64;
  if (row0 >= cnt) return;
  const int col0 = blockIdx.x * 64;
  const float* W = re_w1 + (size_t)e*DIM*INTER_;
  __shared__ float As[16][64];
  __shared__ float Ws[16][64];
  __shared__ int toks[64];
  const int tid = threadIdx.x;
  if (tid < 64) toks[tid] = (row0 + tid < cnt) ? tok_list[e*N_TOK + row0 + tid] : -1;
  __syncthreads();
  const int tm = tid >> 4, tn = tid & 15;
  const int lm = tid >> 2, lk = (tid & 3) * 4;
  const int wk = tid >> 4, wn = (tid & 15) * 4;
  const int tokA = toks[lm];
  float acc[4][4] = {};
  for (int k0 = 0; k0 < DIM; k0 += 16) {
    float4 av;
    if (tokA >= 0) av = *(const float4*)(an + (size_t)tokA*DIM + k0 + lk);
    else { av.x = av.y = av.z = av.w = 0.f; }
    float4 wv = *(const float4*)(W + (size_t)(k0+wk)*INTER_ + col0 + wn);
    As[lk+0][lm] = av.x; As[lk+1][lm] = av.y; As[lk+2][lm] = av.z; As[lk+3][lm] = av.w;
    *(float4*)&Ws[wk][wn] = wv;
    __syncthreads();
    #pragma unroll
    for (int kk = 0; kk < 16; kk++) {
      float a[4], b[4];
      *(float4*)a = *(const float4*)&As[kk][tm*4];
      *(float4*)b = *(const float4*)&Ws[kk][tn*4];
      #pragma unroll
      for (int i = 0; i < 4; i++)
        #pragma unroll
        for (int j = 0; j < 4; j++) acc[i][j] += a[i]*b[j];
    }
    __syncthreads();
  }
  const float* b1 = re_b1 + (size_t)e*INTER_;
  const int off = offs[e];
  #pragma unroll
  for (int i = 0; i < 4; i++) {
    int row = row0 + tm*4 + i;
    if (row >= cnt) continue;
    size_t hrow = (size_t)(off + row) * INTER_;
    #pragma unroll
    for (int j = 0; j < 4; j++) {
      int c = col0 + tn*4 + j;
      h[hrow + c] = gelu_f(acc[i][j] + b1[c]);
    }
  }
}

__global__ __launch_bounds__(256) void moe_ffn2_k(const float* __restrict__ h,
    const float* __restrict__ re_w2, const float* __restrict__ re_b2,
    const int* __restrict__ counts, const int* __restrict__ offs,
    const int* __restrict__ tok_list, const float* __restrict__ gate_list,
    float* __restrict__ out)
{
  const int e = blockIdx.z;
  const int cnt = counts[e];
  const int row0 = blockIdx.y * 64;
  if (row0 >= cnt) return;
  const int col0 = blockIdx.x * 64;
  const float* W = re_w2 + (size_t)e*INTER_*DIM;
  const float* Ab = h + (size_t)offs[e]*INTER_;
  __shared__ float As[16][64];
  __shared__ float Ws[16][64];
  __shared__ int toks[64];
  __shared__ float gts[64];
  const int tid = threadIdx.x;
  if (tid < 64) {
    int ok = (row0 + tid < cnt);
    toks[tid] = ok ? tok_list[e*N_TOK + row0 + tid] : -1;
    gts[tid]  = ok ? gate_list[e*N_TOK + row0 + tid] : 0.f;
  }
  __syncthreads();
  const int tm = tid >> 4, tn = tid & 15;
  const int lm = tid >> 2, lk = (tid & 3) * 4;
  const int wk = tid >> 4, wn = (tid & 15) * 4;
  const bool rowok = (row0 + lm < cnt);
  float acc[4][4] = {};
  for (int k0 = 0; k0 < INTER_; k0 += 16) {
    float4 av;
    if (rowok) av = *(const float4*)(Ab + (size_t)(row0+lm)*INTER_ + k0 + lk);
    else { av.x = av.y = av.z = av.w = 0.f; }
    float4 wv = *(const float4*)(W + (size_t)(k0+wk)*DIM + col0 + wn);
    As[lk+0][lm] = av.x; As[lk+1][lm] = av.y; As[lk+2][lm] = av.z; As[lk+3][lm] = av.w;
    *(float4*)&Ws[wk][wn] = wv;
    __syncthreads();
    #pragma unroll
    for (int kk = 0; kk < 16; kk++) {
      float a[4], b[4];
      *(float4*)a = *(const float4*)&As[kk][tm*4];
      *(float4*)b = *(const float4*)&Ws[kk][tn*4];
      #pragma unroll
      for (int i = 0; i < 4; i++)
        #pragma unroll
        for (int j = 0; j < 4; j++) acc[i][j] += a[i]*b[j];
    }
    __syncthreads();
  }
  const float* b2 = re_b2 + (size_t)e*DIM;
  #pragma unroll
  for (int i = 0; i < 4; i++) {
    int row = row0 + tm*4 + i;
    if (row >= cnt) continue;
    int tok = toks[tm*4 + i];
    float g = gts[tm*4 + i];
    #pragma unroll
    for (int j = 0; j < 4; j++) {
      int c = col0 + tn*4 + j;
      atomicAdd(&out[(size_t)tok*DIM + c], g*(acc[i][j] + b2[c]));
    }
  }
}

// ===================== launch =====================
extern "C" void kernel_launch(void* const* d_in, const int* in_sizes, int n_in,
                              void* d_out, int out_size, void* d_ws, size_t ws_size,
                              hipStream_t stream)
{
  const float* x      = (const float*)d_in[0];
  const float* theta  = (const float*)d_in[2];
  const float* gamma1 = (const float*)d_in[3];
  const float* gamma2 = (const float*)d_in[4];
  const float* q_w = (const float*)d_in[5];
  const float* q_b = (const float*)d_in[6];
  const float* k_w = (const float*)d_in[7];
  const float* k_b = (const float*)d_in[8];
  const float* v_w = (const float*)d_in[9];
  const float* v_b = (const float*)d_in[10];
  const float* o_w = (const float*)d_in[11];
  const float* o_b = (const float*)d_in[12];
  const float* router_w = (const float*)d_in[13];
  const float* router_b = (const float*)d_in[14];
  const float* sh_w1 = (const float*)d_in[15];
  const float* sh_b1 = (const float*)d_in[16];
  const float* sh_w2 = (const float*)d_in[17];
  const float* sh_b2 = (const float*)d_in[18];
  const float* re_w1 = (const float*)d_in[19];
  const float* re_b1 = (const float*)d_in[20];
  const float* re_w2 = (const float*)d_in[21];
  const float* re_b2 = (const float*)d_in[22];
  float* out = (float*)d_out;

  float* wsf = (float*)d_ws;
  const size_t F = (size_t)N_TOK * DIM;     // 2M floats
  float* xn       = wsf + 0*F;
  float* q        = wsf + 1*F;
  float* k        = wsf + 2*F;
  float* v        = wsf + 3*F;
  float* ctx      = wsf + 4*F;
  float* h_moe    = wsf + 1*F;              // reuses q/k/v after attention (3F exactly)
  float* attn_out = wsf + 5*F;
  float* an       = wsf + 6*F;
  float* shh      = wsf + 7*F;
  int*   counts   = (int*)(wsf + 8*F);
  int*   offs     = counts + 32;
  int*   tok_list = counts + 64;
  float* gate_list = (float*)(tok_list + NEXP*N_TOK);

  hipMemsetAsync(counts, 0, 32*sizeof(int), stream);

  dim3 blk(256);
  dim3 gg(16, 32);   // (col tiles, row tiles)

  rmsnorm_k<<<N_TOK, blk, 0, stream>>>(x, gamma1, xn);
  gemm_k<0><<<gg, blk, 0, stream>>>(xn, q_w, q_b, q, nullptr, nullptr, DIM, DIM);
  gemm_k<0><<<gg, blk, 0, stream>>>(xn, k_w, k_b, k, nullptr, nullptr, DIM, DIM);
  gemm_k<0><<<gg, blk, 0, stream>>>(xn, v_w, v_b, v, nullptr, nullptr, DIM, DIM);
  rope_k<<<(N_TOK*NH)/8, blk, 0, stream>>>(q, k, theta);
  attn_k<<<dim3(16, 32), blk, 0, stream>>>(q, k, v, ctx);
  gemm_k<2><<<gg, blk, 0, stream>>>(ctx, o_w, o_b, attn_out, xn, nullptr, DIM, DIM);
  rmsnorm_k<<<N_TOK, blk, 0, stream>>>(attn_out, gamma2, an);
  gemm_k<1><<<gg, blk, 0, stream>>>(an, sh_w1, sh_b1, shh, nullptr, nullptr, DIM, INTER_);
  router_k<<<N_TOK, 64, 0, stream>>>(an, router_w, router_b, counts, tok_list, gate_list);
  scan_k<<<1, 32, 0, stream>>>(counts, offs);
  gemm_k<3><<<gg, blk, 0, stream>>>(shh, sh_w2, sh_b2, out, an, attn_out, INTER_, DIM);
  moe_ffn1_k<<<dim3(16, 32, NEXP), blk, 0, stream>>>(an, re_w1, re_b1, counts, offs, tok_list, h_moe);
  moe_ffn2_k<<<dim3(16, 32, NEXP), blk, 0, stream>>>(h_moe, re_w2, re_b2, counts, offs, tok_list, gate_list, out);
}

// Round 2
// 786.902 us; speedup vs baseline: 2.0756x; 2.0756x over previous
//
#include <hip/hip_runtime.h>
#include <math.h>

typedef unsigned short u16;
typedef short s8v __attribute__((ext_vector_type(8)));
typedef u16 u4v __attribute__((ext_vector_type(4)));
typedef float f4v __attribute__((ext_vector_type(4)));

#define MFMA16(a,b,c) __builtin_amdgcn_mfma_f32_16x16x32_bf16((a),(b),(c),0,0,0)

#define N_TOK 2048
#define SEQ   1024

__device__ __forceinline__ u16 f2b(float f){
  union { float f; unsigned u; } v; v.f = f;
  return (u16)((v.u + 0x7FFFu + ((v.u >> 16) & 1u)) >> 16);
}
__device__ __forceinline__ float gelu_f(float x){
  return 0.5f*x*(1.0f + erff(x*0.70710678118654752f));
}

// ===================== RMSNorm (fp32 + bf16 out) =====================
__global__ __launch_bounds__(256) void rmsnorm_k(const float* __restrict__ x,
    const float* __restrict__ gamma, float* __restrict__ outf, u16* __restrict__ outb)
{
  const int t = blockIdx.x, tid = threadIdx.x;
  const float* xr = x + (size_t)t * 1024;
  float4 xv = *(const float4*)(xr + tid*4);
  float ss = xv.x*xv.x + xv.y*xv.y + xv.z*xv.z + xv.w*xv.w;
  #pragma unroll
  for (int off = 32; off; off >>= 1) ss += __shfl_down(ss, off);
  __shared__ float red[4];
  if ((tid & 63) == 0) red[tid >> 6] = ss;
  __syncthreads();
  float inv = rsqrtf((red[0]+red[1]+red[2]+red[3]) * (1.0f/1024.0f) + 1e-5f);
  float4 gv = *(const float4*)(gamma + tid*4);
  float4 o;
  o.x = xv.x*inv*gv.x; o.y = xv.y*inv*gv.y; o.z = xv.z*inv*gv.z; o.w = xv.w*inv*gv.w;
  *(float4*)(outf + (size_t)t*1024 + tid*4) = o;
  u4v ob = { f2b(o.x), f2b(o.y), f2b(o.z), f2b(o.w) };
  *(u4v*)(outb + (size_t)t*1024 + tid*4) = ob;
}

// ===================== weight transpose+convert: W[K=1024][N=1024] f32 -> Wt[N][K] bf16 ==========
__device__ __forceinline__ void transT_body(const float* __restrict__ W, u16* __restrict__ Wt)
{
  __shared__ __align__(16) u16 T[64][68];
  const int tid = threadIdx.x;
  const int k0 = blockIdx.x*64, n0 = blockIdx.y*64;
  #pragma unroll
  for (int j = 0; j < 4; j++) {
    int q = j*256 + tid; int r = q >> 4, c4 = q & 15;
    float4 v = *(const float4*)(W + (size_t)(k0 + r)*1024 + n0 + c4*4);
    T[c4*4+0][r] = f2b(v.x); T[c4*4+1][r] = f2b(v.y);
    T[c4*4+2][r] = f2b(v.z); T[c4*4+3][r] = f2b(v.w);
  }
  __syncthreads();
  #pragma unroll
  for (int j = 0; j < 4; j++) {
    int q = j*256 + tid; int n = q >> 4, c4 = q & 15;
    u4v o = *(const u4v*)&T[n][c4*4];
    *(u4v*)(Wt + (size_t)(n0 + n)*1024 + k0 + c4*4) = o;
  }
}

__global__ __launch_bounds__(256) void transT6_k(
    const float* s0, const float* s1, const float* s2,
    const float* s3, const float* s4, const float* s5,
    u16* d0, u16* d1, u16* d2, u16* d3, u16* d4, u16* d5)
{
  const float* S; u16* D;
  switch (blockIdx.z) {
    case 0: S=s0; D=d0; break; case 1: S=s1; D=d1; break;
    case 2: S=s2; D=d2; break; case 3: S=s3; D=d3; break;
    case 4: S=s4; D=d4; break; default: S=s5; D=d5; break;
  }
  transT_body(S, D);
}

__global__ __launch_bounds__(256) void transTe_k(const float* __restrict__ src, u16* __restrict__ dst)
{
  transT_body(src + (size_t)blockIdx.z*1024*1024, dst + (size_t)blockIdx.z*1024*1024);
}

// ===================== V transpose: vb[token][h*64+hd] -> vt[(bh*64+hd)][s] ==========
__global__ __launch_bounds__(256) void transv_k(const u16* __restrict__ vb, u16* __restrict__ vt)
{
  __shared__ __align__(16) u16 T[64][72];
  const int tid = threadIdx.x;
  const int s0 = blockIdx.x*64, bh = blockIdx.y, b = bh>>4, h = bh&15;
  #pragma unroll
  for (int j = 0; j < 16; j++) {
    int q = j*256 + tid; int r = q >> 6, c = q & 63;
    T[c][r] = vb[(size_t)(b*SEQ + s0 + r)*1024 + h*64 + c];
  }
  __syncthreads();
  #pragma unroll
  for (int i = 0; i < 2; i++) {
    int q = tid*2 + i; int rr = q >> 3, c8 = q & 7;
    *(s8v*)(vt + (size_t)(bh*64 + rr)*1024 + s0 + c8*8) = *(const s8v*)&T[rr][c8*8];
  }
}

// ===================== RoPE: f32 q,k -> bf16 qb,kb =====================
__global__ __launch_bounds__(256) void rope_k(const float* __restrict__ q, const float* __restrict__ k,
    const float* __restrict__ theta, u16* __restrict__ qb, u16* __restrict__ kb)
{
  const int tid = threadIdx.x;
  const int p = blockIdx.x * 8 + (tid >> 5);
  const int j = tid & 31;
  const int t = p >> 4, h = p & 15;
  const int s = t & (SEQ - 1);
  float ang = (float)s * theta[j];
  float sn, cs;
  sincosf(ang, &sn, &cs);
  size_t base = (size_t)t*1024 + h*64;
  float q1 = q[base + 2*j], q2 = q[base + 2*j + 1];
  float k1 = k[base + 2*j], k2 = k[base + 2*j + 1];
  qb[base + j]      = f2b(q1*cs - q2*sn);
  qb[base + j + 32] = f2b(q1*sn + q2*cs);
  kb[base + j]      = f2b(k1*cs - k2*sn);
  kb[base + j + 32] = f2b(k1*sn + k2*cs);
}

// ===================== MFMA GEMM =====================
// C[2048 or cnt][1024] = A[.,1024](bf16) @ Wt^T ; Wt[N=1024][K=1024] bf16 (pre-transposed)
// MODE 7: QKV fused (wsel by blockIdx.x>>3; q,k f32; v bf16)
// MODE 3: outf = acc + bias + add1
// MODE 2: outb = bf16(gelu(acc+bias))
// MODE 4: outf = acc + bias + add1 + add2
// MODE 5: MoE up: gather rows via gidx, gelu -> outb at offs[e]+row
// MODE 6: MoE down: A at offs[e], atomicAdd gated into outf
template<int MODE>
__global__ __launch_bounds__(256) void mmk(
    const u16* __restrict__ A,
    const u16* __restrict__ Wt0, const u16* __restrict__ Wt1, const u16* __restrict__ Wt2,
    const float* __restrict__ bias0, const float* __restrict__ bias1, const float* __restrict__ bias2,
    float* __restrict__ outf, float* __restrict__ outf1, u16* __restrict__ outb,
    const float* __restrict__ add1, const float* __restrict__ add2,
    const int* __restrict__ gidx, const float* __restrict__ gatel,
    const int* __restrict__ counts, const int* __restrict__ offs)
{
  __shared__ __align__(16) u16 As[128][40];
  __shared__ __align__(16) u16 Bs[128][40];
  __shared__ int toks[128];
  __shared__ float gts[128];

  const int tid = threadIdx.x;
  const int wave = tid >> 6, lane = tid & 63, quad = lane >> 4, l15 = lane & 15;
  int row0 = blockIdx.y * 128;
  int col0 = blockIdx.x * 128;
  const u16* Wt = Wt0;
  const float* bias = bias0;
  const u16* Ab = A;
  int wsel = 0, e = 0, cnt = 0, off_e = 0;

  if (MODE == 7) {
    wsel = blockIdx.x >> 3;
    col0 = (blockIdx.x & 7) * 128;
    Wt   = (wsel == 0) ? Wt0 : ((wsel == 1) ? Wt1 : Wt2);
    bias = (wsel == 0) ? bias0 : ((wsel == 1) ? bias1 : bias2);
  }
  if (MODE == 5 || MODE == 6) {
    e = blockIdx.z;
    cnt = counts[e];
    if (row0 >= cnt) return;
    Wt = Wt0 + (size_t)e * 1024 * 1024;
    bias = bias0 + e * 1024;
    off_e = offs[e];
    if (MODE == 6) Ab = A + (size_t)off_e * 1024;
    if (tid < 128) {
      int ok = (row0 + tid) < cnt;
      toks[tid] = ok ? gidx[e * N_TOK + row0 + tid] : -1;
      gts[tid]  = (ok && MODE == 6) ? gatel[e * N_TOK + row0 + tid] : 0.f;
    }
    __syncthreads();
  }

  const int ar_l = tid >> 1;             // local row for staging (A and B)
  const int ac0  = (tid & 1) * 16;       // k element offset
  long arow;
  if (MODE == 5)      arow = toks[ar_l];
  else if (MODE == 6) { int rr = row0 + ar_l; if (rr >= cnt) rr = cnt - 1; arow = rr; }
  else                arow = row0 + ar_l;
  const long brow = col0 + ar_l;

  f4v acc[4][4];
  #pragma unroll
  for (int i = 0; i < 4; i++)
    #pragma unroll
    for (int j = 0; j < 4; j++)
      acc[i][j] = (f4v){0.f,0.f,0.f,0.f};

  const int wr = (wave >> 1) * 64, wc = (wave & 1) * 64;

  for (int k0 = 0; k0 < 1024; k0 += 32) {
    __syncthreads();
    s8v av0, av1;
    if (MODE == 5 && arow < 0) {
      av0 = (s8v){0,0,0,0,0,0,0,0}; av1 = av0;
    } else {
      const u16* ap = Ab + (size_t)arow * 1024 + k0 + ac0;
      av0 = *(const s8v*)ap; av1 = *(const s8v*)(ap + 8);
    }
    const u16* bp = Wt + (size_t)brow * 1024 + k0 + ac0;
    s8v bv0 = *(const s8v*)bp, bv1 = *(const s8v*)(bp + 8);
    *(s8v*)&As[ar_l][ac0]     = av0;
    *(s8v*)&As[ar_l][ac0 + 8] = av1;
    *(s8v*)&Bs[ar_l][ac0]     = bv0;
    *(s8v*)&Bs[ar_l][ac0 + 8] = bv1;
    __syncthreads();
    s8v af[4], bfr[4];
    #pragma unroll
    for (int mt = 0; mt < 4; mt++) af[mt]  = *(const s8v*)&As[wr + mt*16 + l15][quad*8];
    #pragma unroll
    for (int nt = 0; nt < 4; nt++) bfr[nt] = *(const s8v*)&Bs[wc + nt*16 + l15][quad*8];
    #pragma unroll
    for (int mt = 0; mt < 4; mt++)
      #pragma unroll
      for (int nt = 0; nt < 4; nt++)
        acc[mt][nt] = MFMA16(af[mt], bfr[nt], acc[mt][nt]);
  }

  #pragma unroll
  for (int mt = 0; mt < 4; mt++) {
    #pragma unroll
    for (int reg = 0; reg < 4; reg++) {
      const int lr = wr + mt*16 + quad*4 + reg;
      const size_t gr = row0 + lr;
      #pragma unroll
      for (int nt = 0; nt < 4; nt++) {
        const int n = wc + nt*16 + l15 + col0;
        float v = acc[mt][nt][reg] + bias[n - col0 + col0]; // bias indexed by n within N=1024
        if (MODE == 7) {
          if (wsel == 0)      outf [gr*1024 + n] = v;
          else if (wsel == 1) outf1[gr*1024 + n] = v;
          else                outb [gr*1024 + n] = f2b(v);
        } else if (MODE == 3) {
          outf[gr*1024 + n] = v + add1[gr*1024 + n];
        } else if (MODE == 2) {
          outb[gr*1024 + n] = f2b(gelu_f(v));
        } else if (MODE == 4) {
          outf[gr*1024 + n] = v + add1[gr*1024 + n] + add2[gr*1024 + n];
        } else if (MODE == 5) {
          if (row0 + lr < cnt)
            outb[(size_t)(off_e + row0 + lr)*1024 + n] = f2b(gelu_f(v));
        } else if (MODE == 6) {
          if (row0 + lr < cnt)
            atomicAdd(&outf[(size_t)toks[lr]*1024 + n], gts[lr] * v);
        }
      }
    }
  }
}

// ===================== MFMA flash attention (causal) =====================
__global__ __launch_bounds__(256) void attn_k(const u16* __restrict__ qg,
    const u16* __restrict__ kg, const u16* __restrict__ vtg, u16* __restrict__ ctx)
{
  const int qt = blockIdx.x, bh = blockIdx.y, b = bh >> 4, h = bh & 15;
  const int tid = threadIdx.x, wave = tid >> 6, lane = tid & 63;
  const int quad = lane >> 4, l15 = lane & 15;
  __shared__ __align__(16) u16 Ks[64][72];
  __shared__ __align__(16) u16 Vt[64][72];
  __shared__ __align__(16) u16 Ps[4][16][72];

  s8v aq0, aq1;
  {
    const size_t qrow = (size_t)(b*SEQ + qt*64 + wave*16 + l15);
    aq0 = *(const s8v*)(qg + qrow*1024 + h*64 + quad*8);
    aq1 = *(const s8v*)(qg + qrow*1024 + h*64 + 32 + quad*8);
  }
  f4v oac[4];
  #pragma unroll
  for (int i = 0; i < 4; i++) oac[i] = (f4v){0.f,0.f,0.f,0.f};
  float mi[4] = {-INFINITY,-INFINITY,-INFINITY,-INFINITY};
  float li[4] = {0.f,0.f,0.f,0.f};

  for (int kt = 0; kt <= qt; kt++) {
    __syncthreads();
    #pragma unroll
    for (int ii = 0; ii < 2; ii++) {
      int c = tid*2 + ii, r = c >> 3, c8 = c & 7;
      *(s8v*)&Ks[r][c8*8] = *(const s8v*)(kg + (size_t)(b*SEQ + kt*64 + r)*1024 + h*64 + c8*8);
      *(s8v*)&Vt[r][c8*8] = *(const s8v*)(vtg + (size_t)(bh*64 + r)*1024 + kt*64 + c8*8);
    }
    __syncthreads();

    // S = Q K^T
    f4v s[4];
    #pragma unroll
    for (int nt = 0; nt < 4; nt++) {
      f4v z = (f4v){0.f,0.f,0.f,0.f};
      s8v bk0 = *(const s8v*)&Ks[nt*16 + l15][quad*8];
      s8v bk1 = *(const s8v*)&Ks[nt*16 + l15][32 + quad*8];
      z = MFMA16(aq0, bk0, z);
      z = MFMA16(aq1, bk1, z);
      s[nt] = z;
    }
    // mask + scale
    float sc[4][4];
    const int rowl = wave*16 + quad*4;           // local q row base
    #pragma unroll
    for (int nt = 0; nt < 4; nt++) {
      #pragma unroll
      for (int r = 0; r < 4; r++) {
        float v = s[nt][r] * 0.125f;
        if (kt == qt && (nt*16 + l15) > (rowl + r)) v = -INFINITY;
        sc[nt][r] = v;
      }
    }
    // row stats
    float alpha[4];
    #pragma unroll
    for (int r = 0; r < 4; r++) {
      float v0 = fmaxf(fmaxf(sc[0][r], sc[1][r]), fmaxf(sc[2][r], sc[3][r]));
      v0 = fmaxf(v0, __shfl_xor(v0, 1));
      v0 = fmaxf(v0, __shfl_xor(v0, 2));
      v0 = fmaxf(v0, __shfl_xor(v0, 4));
      v0 = fmaxf(v0, __shfl_xor(v0, 8));
      float mnew = fmaxf(mi[r], v0);
      alpha[r] = __expf(mi[r] - mnew);
      mi[r] = mnew;
    }
    float psum[4] = {0.f,0.f,0.f,0.f};
    #pragma unroll
    for (int nt = 0; nt < 4; nt++) {
      #pragma unroll
      for (int r = 0; r < 4; r++) {
        float p = __expf(sc[nt][r] - mi[r]);
        psum[r] += p;
        Ps[wave][quad*4 + r][nt*16 + l15] = f2b(p);
      }
    }
    #pragma unroll
    for (int r = 0; r < 4; r++) {
      float ps = psum[r];
      ps += __shfl_xor(ps, 1);
      ps += __shfl_xor(ps, 2);
      ps += __shfl_xor(ps, 4);
      ps += __shfl_xor(ps, 8);
      li[r] = li[r]*alpha[r] + ps;
    }
    #pragma unroll
    for (int ht = 0; ht < 4; ht++) {
      f4v o = oac[ht];
      o[0] *= alpha[0]; o[1] *= alpha[1]; o[2] *= alpha[2]; o[3] *= alpha[3];
      oac[ht] = o;
    }
    asm volatile("s_waitcnt lgkmcnt(0)" ::: "memory");
    // PV
    s8v pf0 = *(const s8v*)&Ps[wave][l15][quad*8];
    s8v pf1 = *(const s8v*)&Ps[wave][l15][32 + quad*8];
    #pragma unroll
    for (int ht = 0; ht < 4; ht++) {
      s8v vf0 = *(const s8v*)&Vt[ht*16 + l15][quad*8];
      s8v vf1 = *(const s8v*)&Vt[ht*16 + l15][32 + quad*8];
      oac[ht] = MFMA16(pf0, vf0, oac[ht]);
      oac[ht] = MFMA16(pf1, vf1, oac[ht]);
    }
  }
  float inv[4];
  #pragma unroll
  for (int r = 0; r < 4; r++) inv[r] = 1.f / li[r];
  #pragma unroll
  for (int ht = 0; ht < 4; ht++) {
    #pragma unroll
    for (int r = 0; r < 4; r++) {
      size_t row = (size_t)(b*SEQ + qt*64 + wave*16 + quad*4 + r);
      ctx[row*1024 + h*64 + ht*16 + l15] = f2b(oac[ht][r] * inv[r]);
    }
  }
}

// ===================== Router + top-3 =====================
__global__ __launch_bounds__(256) void router_k(const float* __restrict__ an,
    const float* __restrict__ rw, const float* __restrict__ rb,
    int* __restrict__ counts, int* __restrict__ tok_list, float* __restrict__ gate_list)
{
  const int t = blockIdx.x, tid = threadIdx.x;
  const int e = tid & 31, ch = tid >> 5;
  float part = 0.f;
  if (e < 31) {
    const float* ar = an + (size_t)t*1024 + ch*128;
    const float* wp = rw + (size_t)(ch*128)*31 + e;
    #pragma unroll 8
    for (int d = 0; d < 128; d++) part += ar[d] * wp[d*31];
  }
  __shared__ float red[8][32];
  __shared__ float lgs[32];
  red[ch][e] = part;
  __syncthreads();
  if (tid < 31) {
    float s = 0.f;
    #pragma unroll
    for (int c = 0; c < 8; c++) s += red[c][tid];
    lgs[tid] = s + rb[tid];
  }
  __syncthreads();
  if (tid == 0) {
    float m = -1e30f;
    for (int i = 0; i < 31; i++) m = fmaxf(m, lgs[i]);
    float den = 0.f;
    for (int i = 0; i < 31; i++) den += __expf(lgs[i] - m);
    float invd = 1.f/den;
    unsigned used = 0;
    for (int kk = 0; kk < 3; kk++) {
      int best = 0; float bv = -3e30f;
      for (int i = 0; i < 31; i++) if (!((used>>i)&1u) && lgs[i] > bv) { bv = lgs[i]; best = i; }
      used |= (1u << best);
      float gate = __expf(lgs[best] - m) * invd;
      int slot = atomicAdd(&counts[best], 1);
      tok_list[best*N_TOK + slot] = t;
      gate_list[best*N_TOK + slot] = gate;
    }
  }
}

__global__ void scan_k(const int* __restrict__ counts, int* __restrict__ offs){
  if (threadIdx.x == 0) { int s = 0; for (int i = 0; i < 31; i++){ offs[i] = s; s += counts[i]; } }
}

// ===================== launch =====================
extern "C" void kernel_launch(void* const* d_in, const int* in_sizes, int n_in,
                              void* d_out, int out_size, void* d_ws, size_t ws_size,
                              hipStream_t stream)
{
  const float* x      = (const float*)d_in[0];
  const float* theta  = (const float*)d_in[2];
  const float* gamma1 = (const float*)d_in[3];
  const float* gamma2 = (const float*)d_in[4];
  const float* q_w = (const float*)d_in[5];
  const float* q_b = (const float*)d_in[6];
  const float* k_w = (const float*)d_in[7];
  const float* k_b = (const float*)d_in[8];
  const float* v_w = (const float*)d_in[9];
  const float* v_b = (const float*)d_in[10];
  const float* o_w = (const float*)d_in[11];
  const float* o_b = (const float*)d_in[12];
  const float* router_w = (const float*)d_in[13];
  const float* router_b = (const float*)d_in[14];
  const float* sh_w1 = (const float*)d_in[15];
  const float* sh_b1 = (const float*)d_in[16];
  const float* sh_w2 = (const float*)d_in[17];
  const float* sh_b2 = (const float*)d_in[18];
  const float* re_w1 = (const float*)d_in[19];
  const float* re_b1 = (const float*)d_in[20];
  const float* re_w2 = (const float*)d_in[21];
  const float* re_b2 = (const float*)d_in[22];
  float* out = (float*)d_out;

  char* p = (char*)d_ws;
  auto alloc = [&](size_t bytes) -> void* {
    void* r = (void*)p; p += (bytes + 255) & ~(size_t)255; return r;
  };
  const size_t F32 = (size_t)N_TOK*1024*4;
  const size_t B16 = (size_t)N_TOK*1024*2;
  float* xn       = (float*)alloc(F32);
  float* qf       = (float*)alloc(F32);
  float* kf       = (float*)alloc(F32);
  float* attn_out = (float*)alloc(F32);
  float* an       = (float*)alloc(F32);
  u16* xnb  = (u16*)alloc(B16);
  u16* anb  = (u16*)alloc(B16);
  u16* qb   = (u16*)alloc(B16);
  u16* kb   = (u16*)alloc(B16);
  u16* vb   = (u16*)alloc(B16);
  u16* vt   = (u16*)alloc(B16);
  u16* ctxb = (u16*)alloc(B16);
  u16* shhb = (u16*)alloc(B16);
  u16* hmoe = (u16*)alloc((size_t)3*N_TOK*1024*2);
  u16* wtq  = (u16*)alloc((size_t)1024*1024*2);
  u16* wtk  = (u16*)alloc((size_t)1024*1024*2);
  u16* wtv  = (u16*)alloc((size_t)1024*1024*2);
  u16* wto  = (u16*)alloc((size_t)1024*1024*2);
  u16* wts1 = (u16*)alloc((size_t)1024*1024*2);
  u16* wts2 = (u16*)alloc((size_t)1024*1024*2);
  u16* wte  = (u16*)alloc((size_t)31*1024*1024*2);
  int* counts = (int*)alloc(128);
  int* offs   = (int*)alloc(128);
  int* tok_list = (int*)alloc((size_t)31*N_TOK*4);
  float* gate_list = (float*)alloc((size_t)31*N_TOK*4);

  hipMemsetAsync(counts, 0, 128, stream);

  // weight converts
  transT6_k<<<dim3(16,16,6), 256, 0, stream>>>(q_w, k_w, v_w, o_w, sh_w1, sh_w2,
                                               wtq, wtk, wtv, wto, wts1, wts2);
  transTe_k<<<dim3(16,16,31), 256, 0, stream>>>(re_w1, wte);

  rmsnorm_k<<<N_TOK, 256, 0, stream>>>(x, gamma1, xn, xnb);

  // QKV fused
  mmk<7><<<dim3(24,16), 256, 0, stream>>>(xnb, wtq, wtk, wtv, q_b, k_b, v_b,
      qf, kf, vb, nullptr, nullptr, nullptr, nullptr, nullptr, nullptr);

  rope_k<<<(N_TOK*16)/8, 256, 0, stream>>>(qf, kf, theta, qb, kb);
  transv_k<<<dim3(16,32), 256, 0, stream>>>(vb, vt);
  attn_k<<<dim3(16,32), 256, 0, stream>>>(qb, kb, vt, ctxb);

  // O-proj (+xn residual)
  mmk<3><<<dim3(8,16), 256, 0, stream>>>(ctxb, wto, nullptr, nullptr, o_b, nullptr, nullptr,
      attn_out, nullptr, nullptr, xn, nullptr, nullptr, nullptr, nullptr, nullptr);

  rmsnorm_k<<<N_TOK, 256, 0, stream>>>(attn_out, gamma2, an, anb);

  // shared MLP up (gelu -> bf16)
  mmk<2><<<dim3(8,16), 256, 0, stream>>>(anb, wts1, nullptr, nullptr, sh_b1, nullptr, nullptr,
      nullptr, nullptr, shhb, nullptr, nullptr, nullptr, nullptr, nullptr, nullptr);

  router_k<<<N_TOK, 256, 0, stream>>>(an, router_w, router_b, counts, tok_list, gate_list);
  scan_k<<<1, 32, 0, stream>>>(counts, offs);

  // shared MLP down (+an +attn_out) -> d_out
  mmk<4><<<dim3(8,16), 256, 0, stream>>>(shhb, wts2, nullptr, nullptr, sh_b2, nullptr, nullptr,
      out, nullptr, nullptr, an, attn_out, nullptr, nullptr, nullptr, nullptr);

  // MoE up
  mmk<5><<<dim3(8,16,31), 256, 0, stream>>>(anb, wte, nullptr, nullptr, re_b1, nullptr, nullptr,
      nullptr, nullptr, hmoe, nullptr, nullptr, tok_list, nullptr, counts, offs);

  // convert re_w2 into the same buffer (after moe1 is done; stream-ordered)
  transTe_k<<<dim3(16,16,31), 256, 0, stream>>>(re_w2, wte);

  // MoE down: atomicAdd gated into out
  mmk<6><<<dim3(8,16,31), 256, 0, stream>>>(hmoe, wte, nullptr, nullptr, re_b2, nullptr, nullptr,
      out, nullptr, nullptr, nullptr, nullptr, tok_list, gate_list, counts, offs);
}

// Round 3
// 709.376 us; speedup vs baseline: 2.3024x; 1.1093x over previous
//
#include <hip/hip_runtime.h>
#include <math.h>

typedef unsigned short u16;
typedef short s8v __attribute__((ext_vector_type(8)));
typedef u16 u4v __attribute__((ext_vector_type(4)));
typedef float f4v __attribute__((ext_vector_type(4)));

#define MFMA16(a,b,c) __builtin_amdgcn_mfma_f32_16x16x32_bf16((a),(b),(c),0,0,0)
#define GLDS16(g, l) __builtin_amdgcn_global_load_lds( \
    (const __attribute__((address_space(1))) unsigned int*)(g), \
    (__attribute__((address_space(3))) unsigned int*)(l), 16, 0, 0)

#define N_TOK 2048
#define SEQ   1024

__device__ __forceinline__ u16 f2b(float f){
  union { float f; unsigned u; } v; v.f = f;
  return (u16)((v.u + 0x7FFFu + ((v.u >> 16) & 1u)) >> 16);
}
__device__ __forceinline__ float b2f(u16 b){
  union { unsigned u; float f; } v; v.u = ((unsigned)b) << 16; return v.f;
}
__device__ __forceinline__ float gelu_f(float x){
  return 0.5f*x*(1.0f + erff(x*0.70710678118654752f));
}

// ===================== RMSNorm (fp32 + bf16 out) =====================
__global__ __launch_bounds__(256) void rmsnorm_k(const float* __restrict__ x,
    const float* __restrict__ gamma, float* __restrict__ outf, u16* __restrict__ outb)
{
  const int t = blockIdx.x, tid = threadIdx.x;
  const float* xr = x + (size_t)t * 1024;
  float4 xv = *(const float4*)(xr + tid*4);
  float ss = xv.x*xv.x + xv.y*xv.y + xv.z*xv.z + xv.w*xv.w;
  #pragma unroll
  for (int off = 32; off; off >>= 1) ss += __shfl_down(ss, off);
  __shared__ float red[4];
  if ((tid & 63) == 0) red[tid >> 6] = ss;
  __syncthreads();
  float inv = rsqrtf((red[0]+red[1]+red[2]+red[3]) * (1.0f/1024.0f) + 1e-5f);
  float4 gv = *(const float4*)(gamma + tid*4);
  float4 o;
  o.x = xv.x*inv*gv.x; o.y = xv.y*inv*gv.y; o.z = xv.z*inv*gv.z; o.w = xv.w*inv*gv.w;
  *(float4*)(outf + (size_t)t*1024 + tid*4) = o;
  u4v ob = { f2b(o.x), f2b(o.y), f2b(o.z), f2b(o.w) };
  *(u4v*)(outb + (size_t)t*1024 + tid*4) = ob;
}

// ===================== weight transpose+convert: W[K=1024][N=1024] f32 -> Wt[N][K] bf16 ==========
__device__ __forceinline__ void transT_body(const float* __restrict__ W, u16* __restrict__ Wt)
{
  __shared__ __align__(16) u16 T[64][68];
  const int tid = threadIdx.x;
  const int k0 = blockIdx.x*64, n0 = blockIdx.y*64;
  #pragma unroll
  for (int j = 0; j < 4; j++) {
    int q = j*256 + tid; int r = q >> 4, c4 = q & 15;
    float4 v = *(const float4*)(W + (size_t)(k0 + r)*1024 + n0 + c4*4);
    T[c4*4+0][r] = f2b(v.x); T[c4*4+1][r] = f2b(v.y);
    T[c4*4+2][r] = f2b(v.z); T[c4*4+3][r] = f2b(v.w);
  }
  __syncthreads();
  #pragma unroll
  for (int j = 0; j < 4; j++) {
    int q = j*256 + tid; int n = q >> 4, c4 = q & 15;
    u4v o = *(const u4v*)&T[n][c4*4];
    *(u4v*)(Wt + (size_t)(n0 + n)*1024 + k0 + c4*4) = o;
  }
}

__global__ __launch_bounds__(256) void transT6_k(
    const float* s0, const float* s1, const float* s2,
    const float* s3, const float* s4, const float* s5,
    u16* d0, u16* d1, u16* d2, u16* d3, u16* d4, u16* d5)
{
  const float* S; u16* D;
  switch (blockIdx.z) {
    case 0: S=s0; D=d0; break; case 1: S=s1; D=d1; break;
    case 2: S=s2; D=d2; break; case 3: S=s3; D=d3; break;
    case 4: S=s4; D=d4; break; default: S=s5; D=d5; break;
  }
  transT_body(S, D);
}

__global__ __launch_bounds__(256) void transTe_k(const float* __restrict__ src, u16* __restrict__ dst)
{
  transT_body(src + (size_t)blockIdx.z*1024*1024, dst + (size_t)blockIdx.z*1024*1024);
}

// ===================== V transpose: vb[token][h*64+hd] -> vt[(bh*64+hd)][s] ==========
__global__ __launch_bounds__(256) void transv_k(const u16* __restrict__ vb, u16* __restrict__ vt)
{
  __shared__ __align__(16) u16 T[64][72];
  const int tid = threadIdx.x;
  const int s0 = blockIdx.x*64, bh = blockIdx.y, b = bh>>4, h = bh&15;
  #pragma unroll
  for (int j = 0; j < 16; j++) {
    int q = j*256 + tid; int r = q >> 6, c = q & 63;
    T[c][r] = vb[(size_t)(b*SEQ + s0 + r)*1024 + h*64 + c];
  }
  __syncthreads();
  #pragma unroll
  for (int i = 0; i < 2; i++) {
    int q = tid*2 + i; int rr = q >> 3, c8 = q & 7;
    *(s8v*)(vt + (size_t)(bh*64 + rr)*1024 + s0 + c8*8) = *(const s8v*)&T[rr][c8*8];
  }
}

// ===================== RoPE: bf16 q,k -> bf16 qb,kb =====================
__global__ __launch_bounds__(256) void rope_k(const u16* __restrict__ q, const u16* __restrict__ k,
    const float* __restrict__ theta, u16* __restrict__ qb, u16* __restrict__ kb)
{
  const int tid = threadIdx.x;
  const int p = blockIdx.x * 8 + (tid >> 5);
  const int j = tid & 31;
  const int t = p >> 4, h = p & 15;
  const int s = t & (SEQ - 1);
  float ang = (float)s * theta[j];
  float sn, cs;
  sincosf(ang, &sn, &cs);
  size_t base = (size_t)t*1024 + h*64;
  float q1 = b2f(q[base + 2*j]), q2 = b2f(q[base + 2*j + 1]);
  float k1 = b2f(k[base + 2*j]), k2 = b2f(k[base + 2*j + 1]);
  qb[base + j]      = f2b(q1*cs - q2*sn);
  qb[base + j + 32] = f2b(q1*sn + q2*cs);
  kb[base + j]      = f2b(k1*cs - k2*sn);
  kb[base + j + 32] = f2b(k1*sn + k2*cs);
}

// ===================== MFMA GEMM (m97-style: BK=64, global_load_lds, unpadded LDS) ==========
// MODE 7: QKV fused (wsel = blockIdx.x>>3), all outputs bf16
// MODE 3: outf = acc + bias + add1
// MODE 2: outb = bf16(gelu(acc+bias))
// MODE 4: outf = acc + bias + add1 + add2
// MODE 5: MoE up: gather rows via gidx, gelu -> outb at (offs[e]+row)
// MODE 6: MoE down: A at offs[e], write gate*(acc+bias) to outf at (offs[e]+row)
template<int MODE>
__global__ __launch_bounds__(256) void mmk(
    const u16* __restrict__ A,
    const u16* __restrict__ Wt0, const u16* __restrict__ Wt1, const u16* __restrict__ Wt2,
    const float* __restrict__ bias0, const float* __restrict__ bias1, const float* __restrict__ bias2,
    float* __restrict__ outf, u16* __restrict__ outb0, u16* __restrict__ outb1, u16* __restrict__ outb2,
    const float* __restrict__ add1, const float* __restrict__ add2,
    const int* __restrict__ gidx, const float* __restrict__ gatel,
    const int* __restrict__ counts, const int* __restrict__ offs)
{
  __shared__ __align__(16) u16 As[128*64];
  __shared__ __align__(16) u16 Bs[128*64];
  __shared__ int toks[128];
  __shared__ float gts[128];

  const int tid = threadIdx.x;
  const int wave = tid >> 6, lane = tid & 63, quad = lane >> 4, l15 = lane & 15;
  int row0 = blockIdx.y * 128;
  int col0 = blockIdx.x * 128;
  const u16* Wt = Wt0;
  const float* bias = bias0;
  const u16* Ab = A;
  int wsel = 0, e = 0, cnt = 0, off_e = 0;

  if (MODE == 7) {
    wsel = blockIdx.x >> 3;
    col0 = (blockIdx.x & 7) * 128;
    Wt   = (wsel == 0) ? Wt0 : ((wsel == 1) ? Wt1 : Wt2);
    bias = (wsel == 0) ? bias0 : ((wsel == 1) ? bias1 : bias2);
  }
  if (MODE == 5 || MODE == 6) {
    e = blockIdx.z;
    cnt = counts[e];
    if (row0 >= cnt) return;
    Wt = Wt0 + (size_t)e * 1024 * 1024;
    bias = bias0 + e * 1024;
    off_e = offs[e];
    if (MODE == 6) Ab = A + (size_t)off_e * 1024;
    if (tid < 128) {
      int ok = (row0 + tid) < cnt;
      toks[tid] = ok ? gidx[e * N_TOK + row0 + tid] : 0;
      gts[tid]  = (ok && MODE == 6) ? gatel[e * N_TOK + row0 + tid] : 0.f;
    }
    __syncthreads();
  }

  // per-lane staging sources: lane covers 4 A rows + 4 B rows (8 lanes/row, 128B segments)
  const int lr8 = lane >> 3;          // 0..7 : row within 8-row group
  const int lk  = (lane & 7) * 8;     // k element offset (16B granule)
  const u16* aptr[4];
  const u16* bptr[4];
  #pragma unroll
  for (int c = 0; c < 4; c++) {
    const int ar = wave*32 + c*8 + lr8;   // local tile row 0..127
    long garow;
    if (MODE == 5) {
      garow = toks[ar];
    } else if (MODE == 6) {
      int rr = row0 + ar; if (rr >= cnt) rr = cnt - 1; garow = rr;
    } else {
      garow = row0 + ar;
    }
    aptr[c] = Ab + (size_t)garow * 1024 + lk;
    bptr[c] = Wt + (size_t)(col0 + ar) * 1024 + lk;
  }

  f4v acc[4][4];
  #pragma unroll
  for (int i = 0; i < 4; i++)
    #pragma unroll
    for (int j = 0; j < 4; j++)
      acc[i][j] = (f4v){0.f,0.f,0.f,0.f};

  const int wr = (wave >> 1) * 64, wc = (wave & 1) * 64;

  for (int k0 = 0; k0 < 1024; k0 += 64) {
    __syncthreads();
    #pragma unroll
    for (int c = 0; c < 4; c++) {
      GLDS16(aptr[c] + k0, As + (wave*32 + c*8)*64);
      GLDS16(bptr[c] + k0, Bs + (wave*32 + c*8)*64);
    }
    __syncthreads();
    s8v af[2][4], bfr[2][4];
    #pragma unroll
    for (int ks = 0; ks < 2; ks++) {
      #pragma unroll
      for (int mt = 0; mt < 4; mt++) af[ks][mt]  = *(const s8v*)&As[(wr + mt*16 + l15)*64 + ks*32 + quad*8];
      #pragma unroll
      for (int nt = 0; nt < 4; nt++) bfr[ks][nt] = *(const s8v*)&Bs[(wc + nt*16 + l15)*64 + ks*32 + quad*8];
    }
    #pragma unroll
    for (int ks = 0; ks < 2; ks++)
      #pragma unroll
      for (int mt = 0; mt < 4; mt++)
        #pragma unroll
        for (int nt = 0; nt < 4; nt++)
          acc[mt][nt] = MFMA16(af[ks][mt], bfr[ks][nt], acc[mt][nt]);
  }

  #pragma unroll
  for (int mt = 0; mt < 4; mt++) {
    #pragma unroll
    for (int reg = 0; reg < 4; reg++) {
      const int lr = wr + mt*16 + quad*4 + reg;
      const size_t gr = row0 + lr;
      #pragma unroll
      for (int nt = 0; nt < 4; nt++) {
        const int n = wc + nt*16 + l15 + col0;
        float v = acc[mt][nt][reg] + bias[n];
        if (MODE == 7) {
          u16 bv = f2b(v);
          if (wsel == 0)      outb0[gr*1024 + n] = bv;
          else if (wsel == 1) outb1[gr*1024 + n] = bv;
          else                outb2[gr*1024 + n] = bv;
        } else if (MODE == 3) {
          outf[gr*1024 + n] = v + add1[gr*1024 + n];
        } else if (MODE == 2) {
          outb0[gr*1024 + n] = f2b(gelu_f(v));
        } else if (MODE == 4) {
          outf[gr*1024 + n] = v + add1[gr*1024 + n] + add2[gr*1024 + n];
        } else if (MODE == 5) {
          if (row0 + lr < cnt)
            outb0[(size_t)(off_e + row0 + lr)*1024 + n] = f2b(gelu_f(v));
        } else if (MODE == 6) {
          if (row0 + lr < cnt)
            outf[(size_t)(off_e + row0 + lr)*1024 + n] = gts[lr] * v;
        }
      }
    }
  }
}

// ===================== MFMA flash attention (causal) =====================
__global__ __launch_bounds__(256) void attn_k(const u16* __restrict__ qg,
    const u16* __restrict__ kg, const u16* __restrict__ vtg, u16* __restrict__ ctx)
{
  const int qt = blockIdx.x, bh = blockIdx.y, b = bh >> 4, h = bh & 15;
  const int tid = threadIdx.x, wave = tid >> 6, lane = tid & 63;
  const int quad = lane >> 4, l15 = lane & 15;
  __shared__ __align__(16) u16 Ks[64][72];
  __shared__ __align__(16) u16 Vt[64][72];
  __shared__ __align__(16) u16 Ps[4][16][72];

  s8v aq0, aq1;
  {
    const size_t qrow = (size_t)(b*SEQ + qt*64 + wave*16 + l15);
    aq0 = *(const s8v*)(qg + qrow*1024 + h*64 + quad*8);
    aq1 = *(const s8v*)(qg + qrow*1024 + h*64 + 32 + quad*8);
  }
  f4v oac[4];
  #pragma unroll
  for (int i = 0; i < 4; i++) oac[i] = (f4v){0.f,0.f,0.f,0.f};
  float mi[4] = {-INFINITY,-INFINITY,-INFINITY,-INFINITY};
  float li[4] = {0.f,0.f,0.f,0.f};

  for (int kt = 0; kt <= qt; kt++) {
    __syncthreads();
    #pragma unroll
    for (int ii = 0; ii < 2; ii++) {
      int c = tid*2 + ii, r = c >> 3, c8 = c & 7;
      *(s8v*)&Ks[r][c8*8] = *(const s8v*)(kg + (size_t)(b*SEQ + kt*64 + r)*1024 + h*64 + c8*8);
      *(s8v*)&Vt[r][c8*8] = *(const s8v*)(vtg + (size_t)(bh*64 + r)*1024 + kt*64 + c8*8);
    }
    __syncthreads();

    f4v s[4];
    #pragma unroll
    for (int nt = 0; nt < 4; nt++) {
      f4v z = (f4v){0.f,0.f,0.f,0.f};
      s8v bk0 = *(const s8v*)&Ks[nt*16 + l15][quad*8];
      s8v bk1 = *(const s8v*)&Ks[nt*16 + l15][32 + quad*8];
      z = MFMA16(aq0, bk0, z);
      z = MFMA16(aq1, bk1, z);
      s[nt] = z;
    }
    float sc[4][4];
    const int rowl = wave*16 + quad*4;
    #pragma unroll
    for (int nt = 0; nt < 4; nt++) {
      #pragma unroll
      for (int r = 0; r < 4; r++) {
        float v = s[nt][r] * 0.125f;
        if (kt == qt && (nt*16 + l15) > (rowl + r)) v = -INFINITY;
        sc[nt][r] = v;
      }
    }
    float alpha[4];
    #pragma unroll
    for (int r = 0; r < 4; r++) {
      float v0 = fmaxf(fmaxf(sc[0][r], sc[1][r]), fmaxf(sc[2][r], sc[3][r]));
      v0 = fmaxf(v0, __shfl_xor(v0, 1));
      v0 = fmaxf(v0, __shfl_xor(v0, 2));
      v0 = fmaxf(v0, __shfl_xor(v0, 4));
      v0 = fmaxf(v0, __shfl_xor(v0, 8));
      float mnew = fmaxf(mi[r], v0);
      alpha[r] = __expf(mi[r] - mnew);
      mi[r] = mnew;
    }
    float psum[4] = {0.f,0.f,0.f,0.f};
    #pragma unroll
    for (int nt = 0; nt < 4; nt++) {
      #pragma unroll
      for (int r = 0; r < 4; r++) {
        float p = __expf(sc[nt][r] - mi[r]);
        psum[r] += p;
        Ps[wave][quad*4 + r][nt*16 + l15] = f2b(p);
      }
    }
    #pragma unroll
    for (int r = 0; r < 4; r++) {
      float ps = psum[r];
      ps += __shfl_xor(ps, 1);
      ps += __shfl_xor(ps, 2);
      ps += __shfl_xor(ps, 4);
      ps += __shfl_xor(ps, 8);
      li[r] = li[r]*alpha[r] + ps;
    }
    #pragma unroll
    for (int ht = 0; ht < 4; ht++) {
      f4v o = oac[ht];
      o[0] *= alpha[0]; o[1] *= alpha[1]; o[2] *= alpha[2]; o[3] *= alpha[3];
      oac[ht] = o;
    }
    asm volatile("s_waitcnt lgkmcnt(0)" ::: "memory");
    s8v pf0 = *(const s8v*)&Ps[wave][l15][quad*8];
    s8v pf1 = *(const s8v*)&Ps[wave][l15][32 + quad*8];
    #pragma unroll
    for (int ht = 0; ht < 4; ht++) {
      s8v vf0 = *(const s8v*)&Vt[ht*16 + l15][quad*8];
      s8v vf1 = *(const s8v*)&Vt[ht*16 + l15][32 + quad*8];
      oac[ht] = MFMA16(pf0, vf0, oac[ht]);
      oac[ht] = MFMA16(pf1, vf1, oac[ht]);
    }
  }
  float inv[4];
  #pragma unroll
  for (int r = 0; r < 4; r++) inv[r] = 1.f / li[r];
  #pragma unroll
  for (int ht = 0; ht < 4; ht++) {
    #pragma unroll
    for (int r = 0; r < 4; r++) {
      size_t row = (size_t)(b*SEQ + qt*64 + wave*16 + quad*4 + r);
      ctx[row*1024 + h*64 + ht*16 + l15] = f2b(oac[ht][r] * inv[r]);
    }
  }
}

// ===================== Router + top-3 =====================
__global__ __launch_bounds__(256) void router_k(const float* __restrict__ an,
    const float* __restrict__ rw, const float* __restrict__ rb,
    int* __restrict__ counts, int* __restrict__ tok_list, float* __restrict__ gate_list,
    int* __restrict__ tok_e, int* __restrict__ tok_s)
{
  const int t = blockIdx.x, tid = threadIdx.x;
  const int e = tid & 31, ch = tid >> 5;
  float part = 0.f;
  if (e < 31) {
    const float* ar = an + (size_t)t*1024 + ch*128;
    const float* wp = rw + (size_t)(ch*128)*31 + e;
    #pragma unroll 8
    for (int d = 0; d < 128; d++) part += ar[d] * wp[d*31];
  }
  __shared__ float red[8][32];
  __shared__ float lgs[32];
  red[ch][e] = part;
  __syncthreads();
  if (tid < 31) {
    float s = 0.f;
    #pragma unroll
    for (int c = 0; c < 8; c++) s += red[c][tid];
    lgs[tid] = s + rb[tid];
  }
  __syncthreads();
  if (tid == 0) {
    float m = -1e30f;
    for (int i = 0; i < 31; i++) m = fmaxf(m, lgs[i]);
    float den = 0.f;
    for (int i = 0; i < 31; i++) den += __expf(lgs[i] - m);
    float invd = 1.f/den;
    unsigned used = 0;
    for (int kk = 0; kk < 3; kk++) {
      int best = 0; float bv = -3e30f;
      for (int i = 0; i < 31; i++) if (!((used>>i)&1u) && lgs[i] > bv) { bv = lgs[i]; best = i; }
      used |= (1u << best);
      float gate = __expf(lgs[best] - m) * invd;
      int slot = atomicAdd(&counts[best], 1);
      tok_list[best*N_TOK + slot] = t;
      gate_list[best*N_TOK + slot] = gate;
      tok_e[t*3 + kk] = best;
      tok_s[t*3 + kk] = slot;
    }
  }
}

__global__ void scan_k(const int* __restrict__ counts, int* __restrict__ offs){
  if (threadIdx.x == 0) { int s = 0; for (int i = 0; i < 31; i++){ offs[i] = s; s += counts[i]; } }
}

// ===================== final gather-reduce: out[t] += sum_j mo[offs[e_j]+s_j] ==========
__global__ __launch_bounds__(256) void reduce_k(const float* __restrict__ mo,
    const int* __restrict__ tok_e, const int* __restrict__ tok_s,
    const int* __restrict__ offs, float* __restrict__ out)
{
  const int t = blockIdx.x, tid = threadIdx.x;
  float4 acc = *(const float4*)(out + (size_t)t*1024 + tid*4);
  #pragma unroll
  for (int j = 0; j < 3; j++) {
    int e = tok_e[t*3 + j], s = tok_s[t*3 + j];
    const float* row = mo + (size_t)(offs[e] + s) * 1024;
    float4 v = *(const float4*)(row + tid*4);
    acc.x += v.x; acc.y += v.y; acc.z += v.z; acc.w += v.w;
  }
  *(float4*)(out + (size_t)t*1024 + tid*4) = acc;
}

// ===================== launch =====================
extern "C" void kernel_launch(void* const* d_in, const int* in_sizes, int n_in,
                              void* d_out, int out_size, void* d_ws, size_t ws_size,
                              hipStream_t stream)
{
  const float* x      = (const float*)d_in[0];
  const float* theta  = (const float*)d_in[2];
  const float* gamma1 = (const float*)d_in[3];
  const float* gamma2 = (const float*)d_in[4];
  const float* q_w = (const float*)d_in[5];
  const float* q_b = (const float*)d_in[6];
  const float* k_w = (const float*)d_in[7];
  const float* k_b = (const float*)d_in[8];
  const float* v_w = (const float*)d_in[9];
  const float* v_b = (const float*)d_in[10];
  const float* o_w = (const float*)d_in[11];
  const float* o_b = (const float*)d_in[12];
  const float* router_w = (const float*)d_in[13];
  const float* router_b = (const float*)d_in[14];
  const float* sh_w1 = (const float*)d_in[15];
  const float* sh_b1 = (const float*)d_in[16];
  const float* sh_w2 = (const float*)d_in[17];
  const float* sh_b2 = (const float*)d_in[18];
  const float* re_w1 = (const float*)d_in[19];
  const float* re_b1 = (const float*)d_in[20];
  const float* re_w2 = (const float*)d_in[21];
  const float* re_b2 = (const float*)d_in[22];
  float* out = (float*)d_out;

  char* p = (char*)d_ws;
  auto alloc = [&](size_t bytes) -> void* {
    void* r = (void*)p; p += (bytes + 255) & ~(size_t)255; return r;
  };
  const size_t F32 = (size_t)N_TOK*1024*4;
  const size_t B16 = (size_t)N_TOK*1024*2;
  float* xn       = (float*)alloc(F32);
  float* attn_out = (float*)alloc(F32);
  float* an       = (float*)alloc(F32);
  float* mo       = (float*)alloc((size_t)3*N_TOK*1024*4);   // MoE gated partial rows
  u16* xnb  = (u16*)alloc(B16);
  u16* anb  = (u16*)alloc(B16);
  u16* qb0  = (u16*)alloc(B16);
  u16* kb0  = (u16*)alloc(B16);
  u16* vb   = (u16*)alloc(B16);
  u16* qb   = (u16*)alloc(B16);
  u16* kb   = (u16*)alloc(B16);
  u16* vt   = (u16*)alloc(B16);
  u16* ctxb = (u16*)alloc(B16);
  u16* shhb = (u16*)alloc(B16);
  u16* hmoe = (u16*)alloc((size_t)3*N_TOK*1024*2);
  u16* wtq  = (u16*)alloc((size_t)1024*1024*2);
  u16* wtk  = (u16*)alloc((size_t)1024*1024*2);
  u16* wtv  = (u16*)alloc((size_t)1024*1024*2);
  u16* wto  = (u16*)alloc((size_t)1024*1024*2);
  u16* wts1 = (u16*)alloc((size_t)1024*1024*2);
  u16* wts2 = (u16*)alloc((size_t)1024*1024*2);
  u16* wte  = (u16*)alloc((size_t)31*1024*1024*2);
  int* counts = (int*)alloc(128);
  int* offs   = (int*)alloc(128);
  int* tok_list  = (int*)alloc((size_t)31*N_TOK*4);
  float* gate_list = (float*)alloc((size_t)31*N_TOK*4);
  int* tok_e = (int*)alloc((size_t)N_TOK*3*4);
  int* tok_s = (int*)alloc((size_t)N_TOK*3*4);

  hipMemsetAsync(counts, 0, 128, stream);

  transT6_k<<<dim3(16,16,6), 256, 0, stream>>>(q_w, k_w, v_w, o_w, sh_w1, sh_w2,
                                               wtq, wtk, wtv, wto, wts1, wts2);
  transTe_k<<<dim3(16,16,31), 256, 0, stream>>>(re_w1, wte);

  rmsnorm_k<<<N_TOK, 256, 0, stream>>>(x, gamma1, xn, xnb);

  // QKV fused (bf16 outputs)
  mmk<7><<<dim3(24,16), 256, 0, stream>>>(xnb, wtq, wtk, wtv, q_b, k_b, v_b,
      nullptr, qb0, kb0, vb, nullptr, nullptr, nullptr, nullptr, nullptr, nullptr);

  rope_k<<<(N_TOK*16)/8, 256, 0, stream>>>(qb0, kb0, theta, qb, kb);
  transv_k<<<dim3(16,32), 256, 0, stream>>>(vb, vt);
  attn_k<<<dim3(16,32), 256, 0, stream>>>(qb, kb, vt, ctxb);

  // O-proj (+xn residual)
  mmk<3><<<dim3(8,16), 256, 0, stream>>>(ctxb, wto, nullptr, nullptr, o_b, nullptr, nullptr,
      attn_out, nullptr, nullptr, nullptr, xn, nullptr, nullptr, nullptr, nullptr, nullptr);

  rmsnorm_k<<<N_TOK, 256, 0, stream>>>(attn_out, gamma2, an, anb);

  // shared MLP up (gelu -> bf16)
  mmk<2><<<dim3(8,16), 256, 0, stream>>>(anb, wts1, nullptr, nullptr, sh_b1, nullptr, nullptr,
      nullptr, shhb, nullptr, nullptr, nullptr, nullptr, nullptr, nullptr, nullptr, nullptr);

  router_k<<<N_TOK, 256, 0, stream>>>(an, router_w, router_b, counts, tok_list, gate_list, tok_e, tok_s);
  scan_k<<<1, 32, 0, stream>>>(counts, offs);

  // shared MLP down (+an +attn_out) -> d_out
  mmk<4><<<dim3(8,16), 256, 0, stream>>>(shhb, wts2, nullptr, nullptr, sh_b2, nullptr, nullptr,
      out, nullptr, nullptr, nullptr, an, attn_out, nullptr, nullptr, nullptr, nullptr);

  // MoE up (gathered rows, gelu -> hmoe)
  mmk<5><<<dim3(8,16,31), 256, 0, stream>>>(anb, wte, nullptr, nullptr, re_b1, nullptr, nullptr,
      nullptr, hmoe, nullptr, nullptr, nullptr, nullptr, tok_list, nullptr, counts, offs);

  // convert re_w2 into same buffer (stream-ordered after MoE up)
  transTe_k<<<dim3(16,16,31), 256, 0, stream>>>(re_w2, wte);

  // MoE down: gated rows to scratch (no atomics)
  mmk<6><<<dim3(8,16,31), 256, 0, stream>>>(hmoe, wte, nullptr, nullptr, re_b2, nullptr, nullptr,
      mo, nullptr, nullptr, nullptr, nullptr, nullptr, tok_list, gate_list, counts, offs);

  // final per-token reduce of 3 expert rows into out
  reduce_k<<<N_TOK, 256, 0, stream>>>(mo, tok_e, tok_s, offs, out);
}